// Round 6
// baseline (1079.766 us; speedup 1.0000x reference)
//
#include <hip/hip_runtime.h>
#include <stdint.h>

// out[M,N] = x[M,K] @ W'[N,K]^T + bias[N], W' = W + SCALE*(loraB @ loraA)
// M = 16384 (B*S), N = 4096, K = 4096. SCALE = 16/16 = 1.0.
#define M_DIM 16384
#define N_DIM 4096
#define K_DIM 4096
#define LORA_SCALE 1.0f

#define BM 256
#define BN 128
#define BK 32
#define NSTEP (K_DIM / BK)  // 128 K-steps

typedef _Float16 half8 __attribute__((ext_vector_type(8)));
typedef float f32x4 __attribute__((ext_vector_type(4)));

// ---------------------------------------------------------------------------
// Kernel 1 (fused prep), all-streaming:
//  blocks [0, 8192):      W'[n,k] = W[n,k] + sum_r lB[n,r]*lA[r,k] -> f16
//  blocks [8192, 40960):  x fp32 -> f16, 8 elems/thread.
// ---------------------------------------------------------------------------
__global__ __launch_bounds__(256) void prep_kernel(const float* __restrict__ x,
                                                   _Float16* __restrict__ xb,
                                                   const float* __restrict__ W,
                                                   const float* __restrict__ lA,
                                                   const float* __restrict__ lB,
                                                   _Float16* __restrict__ wp) {
    const int t = threadIdx.x;
    const int WBLK = (N_DIM * K_DIM) / (256 * 8);  // 8192

    if (blockIdx.x < WBLK) {
        const size_t base = ((size_t)blockIdx.x * 256 + t) * 8;
        const int n = (int)(base >> 12);           // / K_DIM
        const int k = (int)(base & (K_DIM - 1));
        const int ns = __builtin_amdgcn_readfirstlane(n);
        float Brow[16];
#pragma unroll
        for (int r = 0; r < 16; ++r) Brow[r] = lB[(size_t)ns * 16 + r];

        f32x4 w0 = *(const f32x4*)(W + base);
        f32x4 w1 = *(const f32x4*)(W + base + 4);
        f32x4 d0 = {0.f, 0.f, 0.f, 0.f}, d1 = {0.f, 0.f, 0.f, 0.f};
#pragma unroll
        for (int r = 0; r < 16; ++r) {
            const float* ar = lA + (size_t)r * K_DIM + k;
            f32x4 a0 = *(const f32x4*)ar;
            f32x4 a1 = *(const f32x4*)(ar + 4);
            d0 += Brow[r] * a0;
            d1 += Brow[r] * a1;
        }
        w0 += LORA_SCALE * d0;
        w1 += LORA_SCALE * d1;
        half8 h;
        h[0] = (_Float16)w0[0]; h[1] = (_Float16)w0[1];
        h[2] = (_Float16)w0[2]; h[3] = (_Float16)w0[3];
        h[4] = (_Float16)w1[0]; h[5] = (_Float16)w1[1];
        h[6] = (_Float16)w1[2]; h[7] = (_Float16)w1[3];
        *(half8*)(wp + base) = h;
        return;
    }

    const size_t base = ((size_t)(blockIdx.x - WBLK) * 256 + t) * 8;
    f32x4 a = *(const f32x4*)(x + base);
    f32x4 b = *(const f32x4*)(x + base + 4);
    half8 h;
    h[0] = (_Float16)a[0]; h[1] = (_Float16)a[1];
    h[2] = (_Float16)a[2]; h[3] = (_Float16)a[3];
    h[4] = (_Float16)b[0]; h[5] = (_Float16)b[1];
    h[6] = (_Float16)b[2]; h[7] = (_Float16)b[3];
    *(half8*)(xb + base) = h;
}

// ---------------------------------------------------------------------------
// Kernel 2: 256x128-tile GEMM, BK=32, 8 waves (4m x 2n), wave-tile 64x64
// (acc=64 VGPR) -> 2 blocks/CU (LDS 72 KiB, VGPR capped 128 via
// __launch_bounds__(512,4)). Cross-block TLP hides per-phase sync stalls.
// 3-slot LDS ring, staging 2 steps ahead, counted vmcnt(3), ONE barrier/step.
// C[m,n] = sum_k A[m,k]*B[n,k] + bias[n].
// ---------------------------------------------------------------------------
__device__ __forceinline__ void load_lds16(const void* g, void* l) {
    __builtin_amdgcn_global_load_lds(
        (const __attribute__((address_space(1))) unsigned int*)(uintptr_t)g,
        (__attribute__((address_space(3))) unsigned int*)(uintptr_t)l,
        16, 0, 0);
}

#define BARRIER() do { \
        asm volatile("" ::: "memory"); \
        __builtin_amdgcn_sched_barrier(0); \
        __builtin_amdgcn_s_barrier(); \
        asm volatile("" ::: "memory"); \
    } while (0)
#define WAIT_LGKM0() do { \
        asm volatile("s_waitcnt lgkmcnt(0)" ::: "memory"); \
        __builtin_amdgcn_sched_barrier(0); \
    } while (0)
#define WAIT_VM(N) do { \
        asm volatile("s_waitcnt vmcnt(" #N ")" ::: "memory"); \
        __builtin_amdgcn_sched_barrier(0); \
    } while (0)

__global__ __launch_bounds__(512, 4) void gemm256_kernel(const _Float16* __restrict__ A,
                                                         const _Float16* __restrict__ B,
                                                         const float* __restrict__ bias,
                                                         float* __restrict__ C) {
    // Slots [3][rows][32 f16]; read swizzle k-chunk' = quad ^ ((row>>1)&3);
    // staging pre-swizzles the global source col (both-sides involution).
    __shared__ _Float16 As[3][BM * 32];  // 3 x 16 KiB
    __shared__ _Float16 Bs[3][BN * 32];  // 3 x  8 KiB  -> 72 KiB total

    const int tid  = threadIdx.x;
    const int lane = tid & 63;
    const int wave = tid >> 6;
    const int wm   = wave >> 1;   // 0..3 : m-quarter (64 rows)
    const int wn   = wave & 1;    // 0..1 : n-half (64 cols)
    const int quad = lane >> 4;
    const int r16  = lane & 15;
    const int swz  = (quad ^ ((r16 >> 1) & 3)) << 3;

    // XCD-bijective remap: 2048 wgs -> 256 contiguous tiles per XCD (m-major).
    const int bid = blockIdx.x;
    const int id  = (bid & 7) * 256 + (bid >> 3);
    const int m0  = (id >> 5) * BM;   // 64 m-tiles
    const int n0  = (id & 31) * BN;   // 32 n-tiles

    // Staging: A slot 16 KiB = 1024 chunks (2/thread), B slot 8 KiB (1/thread).
    // Chunk c -> row c>>2, LDS k-chunk c&3, global k-chunk (c&3)^((row>>1)&3).
    const int  srow = tid >> 2;
    const int  scol = (((tid & 3) ^ ((tid >> 3) & 3)) << 3);
    const _Float16* gA = A + (size_t)(m0 + srow) * K_DIM + scol;
    const _Float16* gB = B + (size_t)(n0 + srow) * K_DIM + scol;
    const int ldst0 = tid * 8;
    const int ldst1 = (tid + 512) * 8;

    const int arow = (wm * 64 + r16) * 32 + swz;
    const int brow = (wn * 64 + r16) * 32 + swz;

    f32x4 acc[4][4] = {};
    half8 a[4], b[4];

#define ISSUE(SLOT, T) do { \
        const _Float16* gA_ = gA + (size_t)(T) * 32; \
        load_lds16(gA_, &As[SLOT][ldst0]); \
        load_lds16(gA_ + (size_t)128 * K_DIM, &As[SLOT][ldst1]); \
        load_lds16(gB + (size_t)(T) * 32, &Bs[SLOT][ldst0]); \
    } while (0)

// One K-step: 8 ds_read_b128, optional 3 global_load_lds, lgkm0, 16 MFMA,
// counted vmcnt, one barrier.
#define STEP(SLOT, NXSLOT, TNEXT, DOISS, VMTAIL) do { \
        _Pragma("unroll") \
        for (int i_ = 0; i_ < 4; ++i_) a[i_] = *(const half8*)&As[SLOT][arow + i_ * 512]; \
        _Pragma("unroll") \
        for (int j_ = 0; j_ < 4; ++j_) b[j_] = *(const half8*)&Bs[SLOT][brow + j_ * 512]; \
        if (DOISS) ISSUE(NXSLOT, TNEXT); \
        WAIT_LGKM0(); \
        __builtin_amdgcn_s_setprio(1); \
        _Pragma("unroll") \
        for (int i_ = 0; i_ < 4; ++i_) \
            _Pragma("unroll") \
            for (int j_ = 0; j_ < 4; ++j_) \
                acc[i_][j_] = __builtin_amdgcn_mfma_f32_16x16x32_f16( \
                    a[i_], b[j_], acc[i_][j_], 0, 0, 0); \
        __builtin_amdgcn_s_setprio(0); \
        VMTAIL; \
        BARRIER(); \
    } while (0)

    // Prologue: stage steps 0,1 into slots 0,1; land step 0 (3 still in flight).
    ISSUE(0, 0);
    ISSUE(1, 1);
    WAIT_VM(3);
    BARRIER();

#pragma unroll 1
    for (int ip = 0; ip < 42; ++ip) {  // steps 0..125
        const int t = 3 * ip;
        STEP(0, 2, t + 2, 1, WAIT_VM(3));
        STEP(1, 0, t + 3, 1, WAIT_VM(3));
        STEP(2, 1, t + 4, 1, WAIT_VM(3));
    }
    // Step 126 (slot 0): no issue; drain step 127 fully.
    STEP(0, 0, 0, 0, WAIT_VM(0));
    // Step 127 (slot 1): no issue, no trailing wait needed beyond lgkm.
    {
#pragma unroll
        for (int i_ = 0; i_ < 4; ++i_) a[i_] = *(const half8*)&As[1][arow + i_ * 512];
#pragma unroll
        for (int j_ = 0; j_ < 4; ++j_) b[j_] = *(const half8*)&Bs[1][brow + j_ * 512];
        WAIT_LGKM0();
#pragma unroll
        for (int i_ = 0; i_ < 4; ++i_)
#pragma unroll
            for (int j_ = 0; j_ < 4; ++j_)
                acc[i_][j_] = __builtin_amdgcn_mfma_f32_16x16x32_f16(
                    a[i_], b[j_], acc[i_][j_], 0, 0, 0);
    }

#undef STEP
#undef ISSUE

    // Epilogue: C/D layout col = lane&15 (n), row = quad*4 + reg (m).
#pragma unroll
    for (int j = 0; j < 4; ++j) {
        const int n = n0 + wn * 64 + j * 16 + r16;
        const float bv = bias[n];
#pragma unroll
        for (int i = 0; i < 4; ++i) {
            const int mbase = m0 + wm * 64 + i * 16 + quad * 4;
#pragma unroll
            for (int r = 0; r < 4; ++r) {
                C[(size_t)(mbase + r) * N_DIM + n] = acc[i][j][r] + bv;
            }
        }
    }
}

// ---------------------------------------------------------------------------
extern "C" void kernel_launch(void* const* d_in, const int* in_sizes, int n_in,
                              void* d_out, int out_size, void* d_ws, size_t ws_size,
                              hipStream_t stream) {
    const float* x      = (const float*)d_in[0];  // [4,4096,4096] fp32 -> [M,K]
    const float* weight = (const float*)d_in[1];  // [N,K] fp32
    const float* bias   = (const float*)d_in[2];  // [N] fp32
    const float* lora_A = (const float*)d_in[3];  // [16,K] fp32
    const float* lora_B = (const float*)d_in[4];  // [N,16] fp32
    float* out = (float*)d_out;

    _Float16* xb = (_Float16*)d_ws;                                       // 128 MiB
    _Float16* wp = (_Float16*)((char*)d_ws + (size_t)M_DIM * K_DIM * 2);  // +32 MiB

    // 1) fused streaming prep: W' (8192 blocks) + x->f16 (32768 blocks)
    const int wblk = (N_DIM * K_DIM) / (256 * 8);
    const int xblk = (int)((M_DIM * (size_t)K_DIM) / (256 * 8));
    prep_kernel<<<dim3(wblk + xblk), dim3(256), 0, stream>>>(x, xb, weight, lora_A, lora_B, wp);
    // 2) GEMM + bias (256x128 tiles, 2048 wgs, 2 blocks/CU)
    gemm256_kernel<<<dim3((M_DIM / BM) * (N_DIM / BN)), dim3(512), 0, stream>>>(xb, wp, bias, out);
}